// Round 6
// baseline (746.026 us; speedup 1.0000x reference)
//
#include <hip/hip_runtime.h>
#include <hip/hip_bf16.h>

#define NN 50000
#define EE 800000
#define NTILES 12500
#define BPG 384                     // blocks per graph (main kernel)
#define TPB_TILES 33                // contiguous tiles per block

typedef __attribute__((ext_vector_type(8))) short bf16x8;
typedef __attribute__((ext_vector_type(4))) float f32x4;
typedef __attribute__((ext_vector_type(4))) unsigned u32x4;

// order-preserving float->u32 encoding for atomicMax scatter-max
__device__ __forceinline__ unsigned enc(float f) {
    unsigned u = __float_as_uint(f);
    return u ^ (unsigned)(((int)u >> 31) | 0x80000000);
}
__device__ __forceinline__ float dec(unsigned u) {
    unsigned v = (u & 0x80000000u) ? (u & 0x7FFFFFFFu) : ~u;
    return __uint_as_float(v);
}
__device__ __forceinline__ unsigned short f2bf(float f) {   // RNE (cold path)
    unsigned u = __float_as_uint(f);
    u += 0x7fffu + ((u >> 16) & 1u);
    return (unsigned short)(u >> 16);
}
__device__ __forceinline__ unsigned pk2(float a, float b) { // v_cvt_pk_bf16_f32
    __hip_bfloat162 t = __float22bfloat162_rn(make_float2(a, b));
    unsigned r;
    __builtin_memcpy(&r, &t, 4);
    return r;
}

__global__ void decode_acc(unsigned* __restrict__ acc, int n) {
    int i = blockIdx.x * blockDim.x + threadIdx.x;
    if (i < n) {
        unsigned u = acc[i];
        ((float*)acc)[i] = (u == 0u) ? 0.0f : dec(u);   // empty -> 0.0 (ref)
    }
}

// ---------------- counting sort by destination row ----------------
__global__ void hist_k(const int* __restrict__ ei1, const int* __restrict__ ei2,
                       unsigned* __restrict__ cnt1, unsigned* __restrict__ cnt2) {
    int idx = blockIdx.x * blockDim.x + threadIdx.x;
    if (idx < EE)            atomicAdd(&cnt1[ei1[idx]], 1u);
    else if (idx < 2 * EE)   atomicAdd(&cnt2[ei2[idx - EE]], 1u);
}

// one block per graph; 1024 threads; exclusive prefix sum of 50000 counts
__global__ __launch_bounds__(1024)
void scan_k(const unsigned* __restrict__ cnt1, const unsigned* __restrict__ cnt2,
            unsigned* __restrict__ off1, unsigned* __restrict__ off2,
            unsigned* __restrict__ cur1, unsigned* __restrict__ cur2) {
    const unsigned* cnt = blockIdx.x ? cnt2 : cnt1;
    unsigned* off = blockIdx.x ? off2 : off1;
    unsigned* cur = blockIdx.x ? cur2 : cur1;
    __shared__ unsigned wsum[16];
    __shared__ unsigned carry_s;
    const int tid = threadIdx.x, lane = tid & 63, w = tid >> 6;
    if (tid == 0) carry_s = 0;
    __syncthreads();
    for (int base = 0; base < NN; base += 1024) {
        int i = base + tid;
        unsigned x = (i < NN) ? cnt[i] : 0u;
        unsigned v = x;
        #pragma unroll
        for (int o = 1; o < 64; o <<= 1) {
            unsigned t = __shfl_up(v, o, 64);
            if (lane >= o) v += t;
        }
        if (lane == 63) wsum[w] = v;
        __syncthreads();
        if (w == 0) {
            unsigned s = (lane < 16) ? wsum[lane] : 0u;
            #pragma unroll
            for (int o = 1; o < 16; o <<= 1) {
                unsigned t = __shfl_up(s, o, 64);
                if (lane >= o) s += t;
            }
            if (lane < 16) wsum[lane] = s;
        }
        __syncthreads();
        unsigned wpre = (w > 0) ? wsum[w - 1] : 0u;
        unsigned carry = carry_s;
        unsigned excl = carry + wpre + v - x;
        if (i < NN) { off[i] = excl; cur[i] = excl; }
        __syncthreads();
        if (tid == 1023) carry_s = carry + wsum[15];
        __syncthreads();
    }
    if (tid == 0) off[NN] = EE;
}

__global__ void scatter_k(const int* __restrict__ ei1, const int* __restrict__ ei2,
                          unsigned* __restrict__ cur1, unsigned* __restrict__ cur2,
                          int* __restrict__ sr1, int* __restrict__ sc1,
                          int* __restrict__ sr2, int* __restrict__ sc2) {
    int idx = blockIdx.x * blockDim.x + threadIdx.x;
    if (idx < EE) {
        int r = ei1[idx], c = ei1[EE + idx];
        unsigned p = atomicAdd(&cur1[r], 1u);
        sr1[p] = r; sc1[p] = c;
    } else if (idx < 2 * EE) {
        int e = idx - EE;
        int r = ei2[e], c = ei2[EE + e];
        unsigned p = atomicAdd(&cur2[r], 1u);
        sr2[p] = r; sc2[p] = c;
    }
}

// ---------------- main fused kernel (sorted edges) ----------------
// 256 threads = 4 waves. 3 raw barriers/tile. Per tile: gather (reg-prefetched)
// -> e_lds -> L1 MFMA -> h_lds -> L2 MFMA -> LDS slot-reduce -> ~4 global
// atomicMax rows.
__global__ __launch_bounds__(256, 2)
void edge_mlp(const float* __restrict__ x1, const float* __restrict__ x2,
              const int* __restrict__ sr1, const int* __restrict__ sc1,
              const int* __restrict__ sr2, const int* __restrict__ sc2,
              const float* __restrict__ W1, const float* __restrict__ b1,
              const float* __restrict__ W2, const float* __restrict__ b2,
              unsigned* __restrict__ acc)
{
    __shared__ short e_lds[64 * 128];   // 16 KB, (e&15) XOR-swizzled
    __shared__ short h_lds[64 * 128];   // 16 KB, same swizzle
    __shared__ unsigned red[64 * 64];   // 16 KB, [slot][ch] encoded maxes
    __shared__ int srow[2][64];
    __shared__ int sslot[2][64];

    const int tid  = threadIdx.x;
    const int lane = tid & 63;
    const int l15  = lane & 15;
    const int lg   = lane >> 4;
    const int wid  = tid >> 6;
    const int w_h  = wid & 1;
    const int w_e  = wid >> 1;

    const int g     = (blockIdx.x >= BPG) ? 1 : 0;
    const int bslot = g ? (blockIdx.x - BPG) : blockIdx.x;
    const int* __restrict__ srw = g ? sr2 : sr1;
    const int* __restrict__ scl = g ? sc2 : sc1;
    const float* __restrict__ xc = g ? x2 : x1;
    const int goff = g * 64;

    const int t0 = bslot * TPB_TILES;
    if (t0 >= NTILES) return;
    const int t1 = min(t0 + TPB_TILES, NTILES);

    // clear red once (flush phase keeps it clean thereafter)
    for (int k = tid; k < 4096; k += 256) red[k] = 0u;

    // ---- persistent register weights ----
    bf16x8 a1[4][4];                    // W1^T A-frags [m: hid][s: kstep]
    #pragma unroll
    for (int m = 0; m < 4; ++m)
        #pragma unroll
        for (int s = 0; s < 4; ++s) {
            const float* p = W1 + (size_t)(32 * s + 8 * lg) * 128
                               + (w_h * 64 + 16 * m + l15);
            bf16x8 r;
            #pragma unroll
            for (int i = 0; i < 8; ++i) r[i] = (short)f2bf(p[i * 128]);
            a1[m][s] = r;
        }
    bf16x8 b2f[4][2];                   // W2 B-frags [s: kstep][n: out]
    #pragma unroll
    for (int s = 0; s < 4; ++s)
        #pragma unroll
        for (int n = 0; n < 2; ++n) {
            const float* p = W2 + (size_t)(32 * s + 8 * lg) * 64
                               + (w_h * 32 + 16 * n + l15);
            bf16x8 r;
            #pragma unroll
            for (int i = 0; i < 8; ++i) r[i] = (short)f2bf(p[i * 64]);
            b2f[s][n] = r;
        }
    float4 b1v[4];
    #pragma unroll
    for (int m = 0; m < 4; ++m)
        b1v[m] = *(const float4*)(b1 + w_h * 64 + 16 * m + 4 * lg);
    float b2v[2];
    #pragma unroll
    for (int n = 0; n < 2; ++n) b2v[n] = b2[w_h * 32 + 16 * n + l15];

    // gather mapping: thread owns edge ge, float cols 16*gq..+15
    const int ge = lane;
    const int gq = wid;
    const int swz = (ge & 15) << 3;

    // ---- prologue ----
    int rcur, ccur, rnext, cnext;
    {
        rcur = srw[t0 * 64 + ge];
        ccur = scl[t0 * 64 + ge];
        int tb = min(t0 + 1, t1 - 1);
        rnext = srw[tb * 64 + ge];
        cnext = scl[tb * 64 + ge];
    }
    float4 gp0, gp1, gp2, gp3, gq0, gq1, gq2, gq3;
    {
        const float4* pp = (const float4*)(x1 + (size_t)rcur * 64 + 16 * gq);
        const float4* pq = (const float4*)(xc + (size_t)ccur * 64 + 16 * gq);
        gp0 = pp[0]; gp1 = pp[1]; gp2 = pp[2]; gp3 = pp[3];
        gq0 = pq[0]; gq1 = pq[1]; gq2 = pq[2]; gq3 = pq[3];
    }

    int i = 0;
    for (int t = t0; t < t1; ++t, ++i) {
        const int ib = i & 1;
        // ---- A: srow + e tile from prefetched regs ----
        if (tid < 64) srow[ib][tid] = rcur;      // ge == tid for wave 0
        {
            short* erow = &e_lds[ge * 128];
            u32x4 v;
            v[0] = pk2(gp0.x, gp0.y); v[1] = pk2(gp0.z, gp0.w);
            v[2] = pk2(gp1.x, gp1.y); v[3] = pk2(gp1.z, gp1.w);
            *(u32x4*)&erow[(16 * gq) ^ swz] = v;
            v[0] = pk2(gp2.x, gp2.y); v[1] = pk2(gp2.z, gp2.w);
            v[2] = pk2(gp3.x, gp3.y); v[3] = pk2(gp3.z, gp3.w);
            *(u32x4*)&erow[(16 * gq + 8) ^ swz] = v;
            v[0] = pk2(gq0.x - gp0.x, gq0.y - gp0.y);
            v[1] = pk2(gq0.z - gp0.z, gq0.w - gp0.w);
            v[2] = pk2(gq1.x - gp1.x, gq1.y - gp1.y);
            v[3] = pk2(gq1.z - gp1.z, gq1.w - gp1.w);
            *(u32x4*)&erow[(64 + 16 * gq) ^ swz] = v;
            v[0] = pk2(gq2.x - gp2.x, gq2.y - gp2.y);
            v[1] = pk2(gq2.z - gp2.z, gq2.w - gp2.w);
            v[2] = pk2(gq3.x - gp3.x, gq3.y - gp3.y);
            v[3] = pk2(gq3.z - gp3.z, gq3.w - gp3.w);
            *(u32x4*)&erow[(64 + 16 * gq + 8) ^ swz] = v;
        }
        // slot = lower_bound of own row within sorted tile (wave 0 only)
        asm volatile("s_waitcnt lgkmcnt(0)" ::: "memory");
        if (tid < 64) {
            int r = rcur, lo = 0;
            #pragma unroll
            for (int st = 32; st > 0; st >>= 1)
                if (srow[ib][lo + st - 1] < r) lo += st;
            sslot[ib][tid] = lo;
        }

        // ---- B: rotate idx; prefetch idx(t+2); issue gather(t+1) ----
        rcur = rnext; ccur = cnext;
        {
            int t2 = min(t + 2, t1 - 1);
            rnext = srw[t2 * 64 + ge];
            cnext = scl[t2 * 64 + ge];
        }
        if (t + 1 < t1) {
            const float4* pp = (const float4*)(x1 + (size_t)rcur * 64 + 16 * gq);
            const float4* pq = (const float4*)(xc + (size_t)ccur * 64 + 16 * gq);
            gp0 = pp[0]; gp1 = pp[1]; gp2 = pp[2]; gp3 = pp[3];
            gq0 = pq[0]; gq1 = pq[1]; gq2 = pq[2]; gq3 = pq[3];
        }

        // ---- C: e/srow/sslot visible ----
        asm volatile("s_waitcnt lgkmcnt(0)\n\ts_barrier" ::: "memory");

        // ---- D: layer 1 MFMA, relu, h write ----
        f32x4 acc1[4][2];
        #pragma unroll
        for (int m = 0; m < 4; ++m)
            #pragma unroll
            for (int n = 0; n < 2; ++n) {
                acc1[m][n][0] = b1v[m].x; acc1[m][n][1] = b1v[m].y;
                acc1[m][n][2] = b1v[m].z; acc1[m][n][3] = b1v[m].w;
            }
        __builtin_amdgcn_s_setprio(1);
        #pragma unroll
        for (int s = 0; s < 4; ++s) {
            bf16x8 eb[2];
            #pragma unroll
            for (int n = 0; n < 2; ++n) {
                int e = w_e * 32 + 16 * n + l15;
                int sidx = e * 128 + ((32 * s + 8 * lg) ^ ((e & 15) << 3));
                eb[n] = *(const bf16x8*)&e_lds[sidx];
            }
            #pragma unroll
            for (int m = 0; m < 4; ++m)
                #pragma unroll
                for (int n = 0; n < 2; ++n)
                    acc1[m][n] = __builtin_amdgcn_mfma_f32_16x16x32_bf16(
                        a1[m][s], eb[n], acc1[m][n], 0, 0, 0);
        }
        __builtin_amdgcn_s_setprio(0);
        #pragma unroll
        for (int m = 0; m < 4; ++m)
            #pragma unroll
            for (int n = 0; n < 2; ++n) {
                f32x4 vv = acc1[m][n];
                int e = w_e * 32 + 16 * n + l15;
                int hidc = w_h * 64 + 16 * m + 4 * lg;
                int sidx = e * 128 + (hidc ^ ((e & 15) << 3));
                uint2 w;
                w.x = pk2(fmaxf(vv[0], 0.f), fmaxf(vv[1], 0.f));
                w.y = pk2(fmaxf(vv[2], 0.f), fmaxf(vv[3], 0.f));
                *(uint2*)&h_lds[sidx] = w;
            }

        // ---- E: h visible ----
        asm volatile("s_waitcnt lgkmcnt(0)\n\ts_barrier" ::: "memory");

        // ---- F: layer 2 MFMA ----
        f32x4 acc2[2][2];
        #pragma unroll
        for (int m = 0; m < 2; ++m)
            #pragma unroll
            for (int n = 0; n < 2; ++n) {
                acc2[m][n][0] = b2v[n]; acc2[m][n][1] = b2v[n];
                acc2[m][n][2] = b2v[n]; acc2[m][n][3] = b2v[n];
            }
        __builtin_amdgcn_s_setprio(1);
        #pragma unroll
        for (int s = 0; s < 4; ++s) {
            bf16x8 ha[2];
            #pragma unroll
            for (int m = 0; m < 2; ++m) {
                int e = w_e * 32 + 16 * m + l15;
                int sidx = e * 128 + ((32 * s + 8 * lg) ^ ((e & 15) << 3));
                ha[m] = *(const bf16x8*)&h_lds[sidx];
            }
            #pragma unroll
            for (int m = 0; m < 2; ++m)
                #pragma unroll
                for (int n = 0; n < 2; ++n)
                    acc2[m][n] = __builtin_amdgcn_mfma_f32_16x16x32_bf16(
                        ha[m], b2f[s][n], acc2[m][n], 0, 0, 0);
        }
        __builtin_amdgcn_s_setprio(0);

        // ---- LDS slot-reduce ----
        #pragma unroll
        for (int m = 0; m < 2; ++m)
            #pragma unroll
            for (int n = 0; n < 2; ++n) {
                int ch = w_h * 32 + 16 * n + l15;
                #pragma unroll
                for (int r = 0; r < 4; ++r) {
                    int e_loc = w_e * 32 + 16 * m + 4 * lg + r;
                    atomicMax(&red[sslot[ib][e_loc] * 64 + ch],
                              enc(acc2[m][n][r]));
                }
            }

        // ---- G: reduce done ----
        asm volatile("s_waitcnt lgkmcnt(0)\n\ts_barrier" ::: "memory");

        // ---- flush roots to global + clear ----
        {
            int e = tid >> 2, q = tid & 3;
            if (sslot[ib][e] == e) {
                unsigned rowg = (unsigned)srow[ib][e];
                unsigned* gdst = acc + (size_t)rowg * 128 + goff + q * 16;
                unsigned* rsrc = &red[e * 64 + q * 16];
                #pragma unroll
                for (int j = 0; j < 16; ++j) {
                    unsigned u = rsrc[j];
                    rsrc[j] = 0u;
                    if (u) atomicMax(&gdst[j], u);
                }
            }
        }
    }
}

extern "C" void kernel_launch(void* const* d_in, const int* in_sizes, int n_in,
                              void* d_out, int out_size, void* d_ws, size_t ws_size,
                              hipStream_t stream) {
    const float* x1 = (const float*)d_in[0];
    const float* x2 = (const float*)d_in[1];
    const int*   ei1 = (const int*)d_in[2];
    const int*   ei2 = (const int*)d_in[3];
    const float* W1 = (const float*)d_in[4];
    const float* b1 = (const float*)d_in[5];
    const float* W2 = (const float*)d_in[6];
    const float* b2 = (const float*)d_in[7];
    unsigned* acc = (unsigned*)d_out;

    // workspace layout (u32 units)
    unsigned* w = (unsigned*)d_ws;
    unsigned* cnt1 = w;                     // 50000
    unsigned* cnt2 = w + 50000;             // 50000
    unsigned* off1 = w + 100000;            // 50001
    unsigned* off2 = w + 150002;            // 50001
    unsigned* cur1 = w + 200004;            // 50000
    unsigned* cur2 = w + 250004;            // 50000
    int* sr1 = (int*)(w + 300008);          // 800000
    int* sc1 = (int*)(w + 1100008);         // 800000
    int* sr2 = (int*)(w + 1900008);         // 800000
    int* sc2 = (int*)(w + 2700008);         // 800000

    hipMemsetAsync(cnt1, 0, 100000 * sizeof(unsigned), stream);
    hipLaunchKernelGGL(hist_k, dim3((2 * EE + 255) / 256), dim3(256), 0, stream,
                       ei1, ei2, cnt1, cnt2);
    hipLaunchKernelGGL(scan_k, dim3(2), dim3(1024), 0, stream,
                       cnt1, cnt2, off1, off2, cur1, cur2);
    hipLaunchKernelGGL(scatter_k, dim3((2 * EE + 255) / 256), dim3(256), 0, stream,
                       ei1, ei2, cur1, cur2, sr1, sc1, sr2, sc2);

    const int total = NN * 128;
    hipMemsetAsync(acc, 0, (size_t)total * sizeof(unsigned), stream);
    hipLaunchKernelGGL(edge_mlp, dim3(2 * BPG), dim3(256), 0, stream,
                       x1, x2, sr1, sc1, sr2, sc2, W1, b1, W2, b2, acc);
    hipLaunchKernelGGL(decode_acc, dim3((total + 255) / 256), dim3(256), 0, stream,
                       acc, total);
}

// Round 7
// 506.208 us; speedup vs baseline: 1.4738x; 1.4738x over previous
//
#include <hip/hip_runtime.h>
#include <hip/hip_bf16.h>

#define NN 50000
#define EE 800000
#define NTILES 12500
#define BPG 512                     // blocks per graph

typedef __attribute__((ext_vector_type(8))) short bf16x8;
typedef __attribute__((ext_vector_type(4))) float f32x4;
typedef __attribute__((ext_vector_type(4))) unsigned u32x4;

// order-preserving float->u32 encoding for atomicMax scatter-max
__device__ __forceinline__ unsigned enc(float f) {
    unsigned u = __float_as_uint(f);
    return u ^ (unsigned)(((int)u >> 31) | 0x80000000);   // 2 VALU ops
}
__device__ __forceinline__ float dec(unsigned u) {
    unsigned v = (u & 0x80000000u) ? (u & 0x7FFFFFFFu) : ~u;
    return __uint_as_float(v);
}
__device__ __forceinline__ unsigned short f2bf(float f) {   // RNE (cold path)
    unsigned u = __float_as_uint(f);
    u += 0x7fffu + ((u >> 16) & 1u);
    return (unsigned short)(u >> 16);
}
__device__ __forceinline__ unsigned pk2(float a, float b) { // v_cvt_pk_bf16_f32
    __hip_bfloat162 t = __float22bfloat162_rn(make_float2(a, b));
    unsigned r;
    __builtin_memcpy(&r, &t, 4);
    return r;
}

__global__ void decode_acc(unsigned* __restrict__ acc, int n) {
    int i = blockIdx.x * blockDim.x + threadIdx.x;
    if (i < n) {
        unsigned u = acc[i];
        ((float*)acc)[i] = (u == 0u) ? 0.0f : dec(u);   // empty -> 0.0 (ref)
    }
}

// filtered scatter-max: plain load (L1/L2-cacheable), atomic only if we beat
// the cached value. Stale reads are SAFE: max is monotone, so a stale
// "cur >= u" implies the true current >= u.
__device__ __forceinline__ void fmax_at(unsigned* dst, unsigned u) {
    unsigned cur = *dst;
    if (u > cur) atomicMax(dst, u);
}

// 256 threads = 4 waves. Wave (w_h, w_e). Raw s_barrier (2/tile) + register
// prefetch of next tile's gather so global latency hides under MFMA+atomics.
__global__ __launch_bounds__(256, 2)
void edge_mlp(const float* __restrict__ x1, const float* __restrict__ x2,
              const int* __restrict__ ei1, const int* __restrict__ ei2,
              const float* __restrict__ W1, const float* __restrict__ b1,
              const float* __restrict__ W2, const float* __restrict__ b2,
              unsigned* __restrict__ acc)
{
    __shared__ short e_lds[64 * 128];   // 16 KB, (e&15) XOR-swizzled
    __shared__ short h_lds[64 * 128];   // 16 KB, same swizzle
    __shared__ int srow[2][64];         // double-buffered (A(t+1) vs F(t) race)

    const int tid  = threadIdx.x;
    const int lane = tid & 63;
    const int l15  = lane & 15;
    const int lg   = lane >> 4;
    const int wid  = tid >> 6;
    const int w_h  = wid & 1;
    const int w_e  = wid >> 1;

    const int g     = (blockIdx.x >= BPG) ? 1 : 0;
    const int bslot = blockIdx.x & (BPG - 1);
    const int* __restrict__ ei = g ? ei2 : ei1;
    const float* __restrict__ xc = g ? x2 : x1;
    const int goff = g * 64;

    // ---- persistent register weights ----
    bf16x8 a1[4][4];                    // W1^T A-frags [m: hid][s: kstep]
    #pragma unroll
    for (int m = 0; m < 4; ++m)
        #pragma unroll
        for (int s = 0; s < 4; ++s) {
            const float* p = W1 + (size_t)(32 * s + 8 * lg) * 128
                               + (w_h * 64 + 16 * m + l15);
            bf16x8 r;
            #pragma unroll
            for (int i = 0; i < 8; ++i) r[i] = (short)f2bf(p[i * 128]);
            a1[m][s] = r;
        }
    bf16x8 b2f[4][2];                   // W2 B-frags [s: kstep][n: out]
    #pragma unroll
    for (int s = 0; s < 4; ++s)
        #pragma unroll
        for (int n = 0; n < 2; ++n) {
            const float* p = W2 + (size_t)(32 * s + 8 * lg) * 64
                               + (w_h * 32 + 16 * n + l15);
            bf16x8 r;
            #pragma unroll
            for (int i = 0; i < 8; ++i) r[i] = (short)f2bf(p[i * 64]);
            b2f[s][n] = r;
        }
    float4 b1v[4];
    #pragma unroll
    for (int m = 0; m < 4; ++m)
        b1v[m] = *(const float4*)(b1 + w_h * 64 + 16 * m + 4 * lg);
    float b2v[2];
    #pragma unroll
    for (int n = 0; n < 2; ++n) b2v[n] = b2[w_h * 32 + 16 * n + l15];

    // ---- gather mapping: this thread owns edge ge, float cols 16*gq..+15 ----
    const int ge = lane;
    const int gq = wid;                 // column quarter
    const int swz = (ge & 15) << 3;     // XOR swizzle, in shorts (bits 3..6)

    // ---- prologue: idx(t0), idx(t1), issue gather(t0) ----
    int rcur, ccur, rnext, cnext;
    {
        int ta = bslot;
        rcur = ei[ta * 64 + ge];
        ccur = ei[EE + ta * 64 + ge];
        int tb = ta + BPG; if (tb >= NTILES) tb = NTILES - 1;
        rnext = ei[tb * 64 + ge];
        cnext = ei[EE + tb * 64 + ge];
    }
    float4 gp0, gp1, gp2, gp3, gq0, gq1, gq2, gq3;
    {
        const float4* pp = (const float4*)(x1 + (size_t)rcur * 64 + 16 * gq);
        const float4* pq = (const float4*)(xc + (size_t)ccur * 64 + 16 * gq);
        gp0 = pp[0]; gp1 = pp[1]; gp2 = pp[2]; gp3 = pp[3];
        gq0 = pq[0]; gq1 = pq[1]; gq2 = pq[2]; gq3 = pq[3];
    }

    int i = 0;
    for (int t = bslot; t < NTILES; t += BPG, ++i) {
        // ---- A: write e tile (t) from prefetched regs; srow ----
        if (tid < 64) srow[i & 1][tid] = rcur;
        {
            short* erow = &e_lds[ge * 128];
            u32x4 v;
            v[0] = pk2(gp0.x, gp0.y); v[1] = pk2(gp0.z, gp0.w);
            v[2] = pk2(gp1.x, gp1.y); v[3] = pk2(gp1.z, gp1.w);
            *(u32x4*)&erow[(16 * gq) ^ swz] = v;
            v[0] = pk2(gp2.x, gp2.y); v[1] = pk2(gp2.z, gp2.w);
            v[2] = pk2(gp3.x, gp3.y); v[3] = pk2(gp3.z, gp3.w);
            *(u32x4*)&erow[(16 * gq + 8) ^ swz] = v;
            v[0] = pk2(gq0.x - gp0.x, gq0.y - gp0.y);
            v[1] = pk2(gq0.z - gp0.z, gq0.w - gp0.w);
            v[2] = pk2(gq1.x - gp1.x, gq1.y - gp1.y);
            v[3] = pk2(gq1.z - gp1.z, gq1.w - gp1.w);
            *(u32x4*)&erow[(64 + 16 * gq) ^ swz] = v;
            v[0] = pk2(gq2.x - gp2.x, gq2.y - gp2.y);
            v[1] = pk2(gq2.z - gp2.z, gq2.w - gp2.w);
            v[2] = pk2(gq3.x - gp3.x, gq3.y - gp3.y);
            v[3] = pk2(gq3.z - gp3.z, gq3.w - gp3.w);
            *(u32x4*)&erow[(64 + 16 * gq + 8) ^ swz] = v;
        }

        // ---- B: rotate idx; prefetch idx(t+2); issue gather(t+1) ----
        rcur = rnext; ccur = cnext;
        {
            int t2 = t + 2 * BPG; if (t2 >= NTILES) t2 = NTILES - 1;
            rnext = ei[t2 * 64 + ge];
            cnext = ei[EE + t2 * 64 + ge];
        }
        if (t + BPG < NTILES) {
            const float4* pp = (const float4*)(x1 + (size_t)rcur * 64 + 16 * gq);
            const float4* pq = (const float4*)(xc + (size_t)ccur * 64 + 16 * gq);
            gp0 = pp[0]; gp1 = pp[1]; gp2 = pp[2]; gp3 = pp[3];
            gq0 = pq[0]; gq1 = pq[1]; gq2 = pq[2]; gq3 = pq[3];
        }

        // ---- C: LDS visible, raw barrier (no vmcnt drain!) ----
        asm volatile("s_waitcnt lgkmcnt(0)\n\ts_barrier" ::: "memory");

        // ---- D: layer 1 MFMA, relu, h write ----
        f32x4 acc1[4][2];
        #pragma unroll
        for (int m = 0; m < 4; ++m)
            #pragma unroll
            for (int n = 0; n < 2; ++n) {
                acc1[m][n][0] = b1v[m].x; acc1[m][n][1] = b1v[m].y;
                acc1[m][n][2] = b1v[m].z; acc1[m][n][3] = b1v[m].w;
            }
        __builtin_amdgcn_s_setprio(1);
        #pragma unroll
        for (int s = 0; s < 4; ++s) {
            bf16x8 eb[2];
            #pragma unroll
            for (int n = 0; n < 2; ++n) {
                int e = w_e * 32 + 16 * n + l15;
                int sidx = e * 128 + ((32 * s + 8 * lg) ^ ((e & 15) << 3));
                eb[n] = *(const bf16x8*)&e_lds[sidx];
            }
            #pragma unroll
            for (int m = 0; m < 4; ++m)
                #pragma unroll
                for (int n = 0; n < 2; ++n)
                    acc1[m][n] = __builtin_amdgcn_mfma_f32_16x16x32_bf16(
                        a1[m][s], eb[n], acc1[m][n], 0, 0, 0);
        }
        __builtin_amdgcn_s_setprio(0);
        #pragma unroll
        for (int m = 0; m < 4; ++m)
            #pragma unroll
            for (int n = 0; n < 2; ++n) {
                f32x4 vv = acc1[m][n];
                int e = w_e * 32 + 16 * n + l15;
                int hidc = w_h * 64 + 16 * m + 4 * lg;
                int sidx = e * 128 + (hidc ^ ((e & 15) << 3));
                uint2 w;
                w.x = pk2(fmaxf(vv[0], 0.f), fmaxf(vv[1], 0.f));
                w.y = pk2(fmaxf(vv[2], 0.f), fmaxf(vv[3], 0.f));
                *(uint2*)&h_lds[sidx] = w;
            }

        // ---- E: h visible, raw barrier ----
        asm volatile("s_waitcnt lgkmcnt(0)\n\ts_barrier" ::: "memory");

        // ---- F: layer 2 MFMA + filtered scatter-max ----
        f32x4 acc2[2][2];
        #pragma unroll
        for (int m = 0; m < 2; ++m)
            #pragma unroll
            for (int n = 0; n < 2; ++n) {
                acc2[m][n][0] = b2v[n]; acc2[m][n][1] = b2v[n];
                acc2[m][n][2] = b2v[n]; acc2[m][n][3] = b2v[n];
            }
        __builtin_amdgcn_s_setprio(1);
        #pragma unroll
        for (int s = 0; s < 4; ++s) {
            bf16x8 ha[2];
            #pragma unroll
            for (int m = 0; m < 2; ++m) {
                int e = w_e * 32 + 16 * m + l15;
                int sidx = e * 128 + ((32 * s + 8 * lg) ^ ((e & 15) << 3));
                ha[m] = *(const bf16x8*)&h_lds[sidx];
            }
            #pragma unroll
            for (int m = 0; m < 2; ++m)
                #pragma unroll
                for (int n = 0; n < 2; ++n)
                    acc2[m][n] = __builtin_amdgcn_mfma_f32_16x16x32_bf16(
                        ha[m], b2f[s][n], acc2[m][n], 0, 0, 0);
        }
        __builtin_amdgcn_s_setprio(0);
        #pragma unroll
        for (int m = 0; m < 2; ++m) {
            int4 rows = *(const int4*)&srow[i & 1][w_e * 32 + 16 * m + 4 * lg];
            #pragma unroll
            for (int n = 0; n < 2; ++n) {
                int outc = w_h * 32 + 16 * n + l15;
                fmax_at(&acc[(size_t)rows.x * 128 + goff + outc], enc(acc2[m][n][0]));
                fmax_at(&acc[(size_t)rows.y * 128 + goff + outc], enc(acc2[m][n][1]));
                fmax_at(&acc[(size_t)rows.z * 128 + goff + outc], enc(acc2[m][n][2]));
                fmax_at(&acc[(size_t)rows.w * 128 + goff + outc], enc(acc2[m][n][3]));
            }
        }
    }
}

extern "C" void kernel_launch(void* const* d_in, const int* in_sizes, int n_in,
                              void* d_out, int out_size, void* d_ws, size_t ws_size,
                              hipStream_t stream) {
    const float* x1 = (const float*)d_in[0];
    const float* x2 = (const float*)d_in[1];
    const int*   ei1 = (const int*)d_in[2];
    const int*   ei2 = (const int*)d_in[3];
    const float* W1 = (const float*)d_in[4];
    const float* b1 = (const float*)d_in[5];
    const float* W2 = (const float*)d_in[6];
    const float* b2 = (const float*)d_in[7];
    unsigned* acc = (unsigned*)d_out;

    const int total = NN * 128;
    hipMemsetAsync(acc, 0, (size_t)total * sizeof(unsigned), stream);
    hipLaunchKernelGGL(edge_mlp, dim3(2 * BPG), dim3(256), 0, stream,
                       x1, x2, ei1, ei2, W1, b1, W2, b2, acc);
    hipLaunchKernelGGL(decode_acc, dim3((total + 255) / 256), dim3(256), 0, stream,
                       acc, total);
}

// Round 8
// 482.617 us; speedup vs baseline: 1.5458x; 1.0489x over previous
//
#include <hip/hip_runtime.h>
#include <hip/hip_bf16.h>

#define NN 50000
#define EE 800000
#define NTILES 12500
#define BPG 384                     // edge_mlp blocks per graph
#define NB 98                       // scan blocks per graph (98*512 >= 50000)

typedef __attribute__((ext_vector_type(8))) short bf16x8;
typedef __attribute__((ext_vector_type(4))) float f32x4;
typedef __attribute__((ext_vector_type(4))) unsigned u32x4;

// order-preserving float->u32 encoding for atomicMax scatter-max
__device__ __forceinline__ unsigned enc(float f) {
    unsigned u = __float_as_uint(f);
    return u ^ (unsigned)(((int)u >> 31) | 0x80000000);
}
__device__ __forceinline__ float dec(unsigned u) {
    unsigned v = (u & 0x80000000u) ? (u & 0x7FFFFFFFu) : ~u;
    return __uint_as_float(v);
}
__device__ __forceinline__ unsigned short f2bf(float f) {   // RNE (cold path)
    unsigned u = __float_as_uint(f);
    u += 0x7fffu + ((u >> 16) & 1u);
    return (unsigned short)(u >> 16);
}
__device__ __forceinline__ unsigned pk2(float a, float b) { // v_cvt_pk_bf16_f32
    __hip_bfloat162 t = __float22bfloat162_rn(make_float2(a, b));
    unsigned r;
    __builtin_memcpy(&r, &t, 4);
    return r;
}

__global__ void decode_acc(unsigned* __restrict__ acc, int n) {
    int i = blockIdx.x * blockDim.x + threadIdx.x;
    if (i < n) {
        unsigned u = acc[i];
        ((float*)acc)[i] = (u == 0u) ? 0.0f : dec(u);   // empty -> 0.0 (ref)
    }
}

// ---------------- counting sort by destination row ----------------
__global__ void hist_k(const int* __restrict__ ei1, const int* __restrict__ ei2,
                       unsigned* __restrict__ cnt) {          // cnt[2][NN]
    int idx = blockIdx.x * blockDim.x + threadIdx.x;
    if (idx < EE)           atomicAdd(&cnt[ei1[idx]], 1u);
    else if (idx < 2 * EE)  atomicAdd(&cnt[NN + ei2[idx - EE]], 1u);
}

__global__ __launch_bounds__(512)
void partial_k(const unsigned* __restrict__ cnt, unsigned* __restrict__ partial) {
    int g = blockIdx.x / NB, b = blockIdx.x % NB;
    int i = b * 512 + threadIdx.x;
    unsigned x = (i < NN) ? cnt[g * NN + i] : 0u;
    #pragma unroll
    for (int o = 32; o; o >>= 1) x += __shfl_down(x, o, 64);
    __shared__ unsigned ws[8];
    int lane = threadIdx.x & 63, w = threadIdx.x >> 6;
    if (lane == 0) ws[w] = x;
    __syncthreads();
    if (threadIdx.x == 0) {
        unsigned s = 0;
        #pragma unroll
        for (int k = 0; k < 8; ++k) s += ws[k];
        partial[g * NB + b] = s;
    }
}

__global__ __launch_bounds__(128)
void boff_k(const unsigned* __restrict__ partial, unsigned* __restrict__ boff) {
    int g = threadIdx.x >> 6, lane = threadIdx.x & 63;
    const unsigned* p = partial + g * NB;
    unsigned* o = boff + g * NB;
    unsigned x0 = p[lane];                       // NB=98 > 64, all valid
    unsigned v0 = x0;
    #pragma unroll
    for (int d = 1; d < 64; d <<= 1) { unsigned t = __shfl_up(v0, d, 64); if (lane >= d) v0 += t; }
    unsigned sum0 = __shfl(v0, 63, 64);
    unsigned x1 = (64 + lane < NB) ? p[64 + lane] : 0u;
    unsigned v1 = x1;
    #pragma unroll
    for (int d = 1; d < 64; d <<= 1) { unsigned t = __shfl_up(v1, d, 64); if (lane >= d) v1 += t; }
    o[lane] = v0 - x0;
    if (64 + lane < NB) o[64 + lane] = sum0 + v1 - x1;
}

__global__ __launch_bounds__(512)
void cur_k(const unsigned* __restrict__ cnt, const unsigned* __restrict__ boff,
           unsigned* __restrict__ cur) {
    int g = blockIdx.x / NB, b = blockIdx.x % NB;
    int i = b * 512 + threadIdx.x;
    unsigned x = (i < NN) ? cnt[g * NN + i] : 0u;
    int lane = threadIdx.x & 63, w = threadIdx.x >> 6;
    unsigned v = x;
    #pragma unroll
    for (int d = 1; d < 64; d <<= 1) { unsigned t = __shfl_up(v, d, 64); if (lane >= d) v += t; }
    __shared__ unsigned ws[8], wso[8];
    if (lane == 63) ws[w] = v;
    __syncthreads();
    if (threadIdx.x < 8) {
        unsigned s = 0;
        for (int k = 0; k < (int)threadIdx.x; ++k) s += ws[k];
        wso[threadIdx.x] = s;
    }
    __syncthreads();
    if (i < NN) cur[g * NN + i] = boff[g * NB + b] + wso[w] + v - x;
}

__global__ void scatter_k(const int* __restrict__ ei1, const int* __restrict__ ei2,
                          unsigned* __restrict__ cur, uint2* __restrict__ se) {
    int idx = blockIdx.x * blockDim.x + threadIdx.x;
    if (idx < EE) {
        int r = ei1[idx], c = ei1[EE + idx];
        unsigned p = atomicAdd(&cur[r], 1u);
        se[p] = make_uint2((unsigned)r, (unsigned)c);
    } else if (idx < 2 * EE) {
        int e = idx - EE;
        int r = ei2[e], c = ei2[EE + e];
        unsigned p = atomicAdd(&cur[NN + r], 1u);
        se[EE + p] = make_uint2((unsigned)r, (unsigned)c);
    }
}

// scratch word index: bank-conflict-free by construction
__device__ __forceinline__ int widx(int e, int ch) {
    return e * 64 + (ch ^ (((e >> 2) & 3) << 4));
}

// filtered scatter-max (sorted blocks -> loads are L2-local)
__device__ __forceinline__ void fmax_at(unsigned* dst, unsigned u) {
    unsigned c = *dst;
    if (u > c) atomicMax(dst, u);
}

// ---------------- main fused kernel (sorted edges) ----------------
__global__ __launch_bounds__(256, 2)
void edge_mlp(const float* __restrict__ x1, const float* __restrict__ x2,
              const uint2* __restrict__ se,
              const float* __restrict__ W1, const float* __restrict__ b1,
              const float* __restrict__ W2, const float* __restrict__ b2,
              unsigned* __restrict__ acc)
{
    __shared__ short e_lds[64 * 128];     // 16 KB, (e&15) XOR-swizzled
    __shared__ short h_lds[64 * 128];     // 16 KB, same swizzle
    __shared__ unsigned red[64 * 64];     // 16 KB scratch, widx-swizzled f32 bits
    __shared__ int srow[2][64];

    const int tid  = threadIdx.x;
    const int lane = tid & 63;
    const int l15  = lane & 15;
    const int lg   = lane >> 4;
    const int wid  = tid >> 6;
    const int w_h  = wid & 1;
    const int w_e  = wid >> 1;

    const int g     = (blockIdx.x >= BPG) ? 1 : 0;
    const int bslot = g ? (blockIdx.x - BPG) : blockIdx.x;
    const uint2* __restrict__ sed = se + (size_t)g * EE;
    const float* __restrict__ xc = g ? x2 : x1;
    const int goff = g * 64;

    const int t0 = (bslot * NTILES) / BPG;
    const int t1 = ((bslot + 1) * NTILES) / BPG;

    // ---- persistent register weights ----
    bf16x8 a1[4][4];
    #pragma unroll
    for (int m = 0; m < 4; ++m)
        #pragma unroll
        for (int s = 0; s < 4; ++s) {
            const float* p = W1 + (size_t)(32 * s + 8 * lg) * 128
                               + (w_h * 64 + 16 * m + l15);
            bf16x8 r;
            #pragma unroll
            for (int i = 0; i < 8; ++i) r[i] = (short)f2bf(p[i * 128]);
            a1[m][s] = r;
        }
    bf16x8 b2f[4][2];
    #pragma unroll
    for (int s = 0; s < 4; ++s)
        #pragma unroll
        for (int n = 0; n < 2; ++n) {
            const float* p = W2 + (size_t)(32 * s + 8 * lg) * 64
                               + (w_h * 32 + 16 * n + l15);
            bf16x8 r;
            #pragma unroll
            for (int i = 0; i < 8; ++i) r[i] = (short)f2bf(p[i * 64]);
            b2f[s][n] = r;
        }
    float4 b1v[4];
    #pragma unroll
    for (int m = 0; m < 4; ++m)
        b1v[m] = *(const float4*)(b1 + w_h * 64 + 16 * m + 4 * lg);
    float b2v[2];
    #pragma unroll
    for (int n = 0; n < 2; ++n) b2v[n] = b2[w_h * 32 + 16 * n + l15];

    // gather mapping: thread owns edge ge, float cols 16*gq..+15
    const int ge = lane;
    const int gq = wid;
    const int swz = (ge & 15) << 3;

    // ---- prologue ----
    int rcur, ccur, rnext, cnext;
    {
        uint2 a = sed[t0 * 64 + ge];
        rcur = (int)a.x; ccur = (int)a.y;
        int tb = min(t0 + 1, t1 - 1);
        uint2 b = sed[tb * 64 + ge];
        rnext = (int)b.x; cnext = (int)b.y;
    }
    float4 gp0, gp1, gp2, gp3, gq0, gq1, gq2, gq3;
    {
        const float4* pp = (const float4*)(x1 + (size_t)rcur * 64 + 16 * gq);
        const float4* pq = (const float4*)(xc + (size_t)ccur * 64 + 16 * gq);
        gp0 = pp[0]; gp1 = pp[1]; gp2 = pp[2]; gp3 = pp[3];
        gq0 = pq[0]; gq1 = pq[1]; gq2 = pq[2]; gq3 = pq[3];
    }

    int i = 0;
    for (int t = t0; t < t1; ++t, ++i) {
        const int ib = i & 1;
        // ---- A: srow + e tile from prefetched regs ----
        if (tid < 64) srow[ib][tid] = rcur;
        {
            short* erow = &e_lds[ge * 128];
            u32x4 v;
            v[0] = pk2(gp0.x, gp0.y); v[1] = pk2(gp0.z, gp0.w);
            v[2] = pk2(gp1.x, gp1.y); v[3] = pk2(gp1.z, gp1.w);
            *(u32x4*)&erow[(16 * gq) ^ swz] = v;
            v[0] = pk2(gp2.x, gp2.y); v[1] = pk2(gp2.z, gp2.w);
            v[2] = pk2(gp3.x, gp3.y); v[3] = pk2(gp3.z, gp3.w);
            *(u32x4*)&erow[(16 * gq + 8) ^ swz] = v;
            v[0] = pk2(gq0.x - gp0.x, gq0.y - gp0.y);
            v[1] = pk2(gq0.z - gp0.z, gq0.w - gp0.w);
            v[2] = pk2(gq1.x - gp1.x, gq1.y - gp1.y);
            v[3] = pk2(gq1.z - gp1.z, gq1.w - gp1.w);
            *(u32x4*)&erow[(64 + 16 * gq) ^ swz] = v;
            v[0] = pk2(gq2.x - gp2.x, gq2.y - gp2.y);
            v[1] = pk2(gq2.z - gp2.z, gq2.w - gp2.w);
            v[2] = pk2(gq3.x - gp3.x, gq3.y - gp3.y);
            v[3] = pk2(gq3.z - gp3.z, gq3.w - gp3.w);
            *(u32x4*)&erow[(64 + 16 * gq + 8) ^ swz] = v;
        }

        // ---- B: rotate idx; prefetch idx(t+2); issue gather(t+1) ----
        rcur = rnext; ccur = cnext;
        {
            int t2 = min(t + 2, t1 - 1);
            uint2 b = sed[t2 * 64 + ge];
            rnext = (int)b.x; cnext = (int)b.y;
        }
        if (t + 1 < t1) {
            const float4* pp = (const float4*)(x1 + (size_t)rcur * 64 + 16 * gq);
            const float4* pq = (const float4*)(xc + (size_t)ccur * 64 + 16 * gq);
            gp0 = pp[0]; gp1 = pp[1]; gp2 = pp[2]; gp3 = pp[3];
            gq0 = pq[0]; gq1 = pq[1]; gq2 = pq[2]; gq3 = pq[3];
        }

        // ---- C: e/srow visible ----
        asm volatile("s_waitcnt lgkmcnt(0)\n\ts_barrier" ::: "memory");

        // ---- D: layer 1 MFMA, relu, h write ----
        f32x4 acc1[4][2];
        #pragma unroll
        for (int m = 0; m < 4; ++m)
            #pragma unroll
            for (int n = 0; n < 2; ++n) {
                acc1[m][n][0] = b1v[m].x; acc1[m][n][1] = b1v[m].y;
                acc1[m][n][2] = b1v[m].z; acc1[m][n][3] = b1v[m].w;
            }
        __builtin_amdgcn_s_setprio(1);
        #pragma unroll
        for (int s = 0; s < 4; ++s) {
            bf16x8 eb[2];
            #pragma unroll
            for (int n = 0; n < 2; ++n) {
                int e = w_e * 32 + 16 * n + l15;
                int sidx = e * 128 + ((32 * s + 8 * lg) ^ ((e & 15) << 3));
                eb[n] = *(const bf16x8*)&e_lds[sidx];
            }
            #pragma unroll
            for (int m = 0; m < 4; ++m)
                #pragma unroll
                for (int n = 0; n < 2; ++n)
                    acc1[m][n] = __builtin_amdgcn_mfma_f32_16x16x32_bf16(
                        a1[m][s], eb[n], acc1[m][n], 0, 0, 0);
        }
        __builtin_amdgcn_s_setprio(0);
        #pragma unroll
        for (int m = 0; m < 4; ++m)
            #pragma unroll
            for (int n = 0; n < 2; ++n) {
                f32x4 vv = acc1[m][n];
                int e = w_e * 32 + 16 * n + l15;
                int hidc = w_h * 64 + 16 * m + 4 * lg;
                int sidx = e * 128 + (hidc ^ ((e & 15) << 3));
                uint2 w;
                w.x = pk2(fmaxf(vv[0], 0.f), fmaxf(vv[1], 0.f));
                w.y = pk2(fmaxf(vv[2], 0.f), fmaxf(vv[3], 0.f));
                *(uint2*)&h_lds[sidx] = w;
            }

        // ---- E: h visible ----
        asm volatile("s_waitcnt lgkmcnt(0)\n\ts_barrier" ::: "memory");

        // ---- F: layer 2 MFMA + scratch write ----
        f32x4 acc2[2][2];
        #pragma unroll
        for (int m = 0; m < 2; ++m)
            #pragma unroll
            for (int n = 0; n < 2; ++n) {
                acc2[m][n][0] = b2v[n]; acc2[m][n][1] = b2v[n];
                acc2[m][n][2] = b2v[n]; acc2[m][n][3] = b2v[n];
            }
        __builtin_amdgcn_s_setprio(1);
        #pragma unroll
        for (int s = 0; s < 4; ++s) {
            bf16x8 ha[2];
            #pragma unroll
            for (int m = 0; m < 2; ++m) {
                int e = w_e * 32 + 16 * m + l15;
                int sidx = e * 128 + ((32 * s + 8 * lg) ^ ((e & 15) << 3));
                ha[m] = *(const bf16x8*)&h_lds[sidx];
            }
            #pragma unroll
            for (int m = 0; m < 2; ++m)
                #pragma unroll
                for (int n = 0; n < 2; ++n)
                    acc2[m][n] = __builtin_amdgcn_mfma_f32_16x16x32_bf16(
                        ha[m], b2f[s][n], acc2[m][n], 0, 0, 0);
        }
        __builtin_amdgcn_s_setprio(0);
        #pragma unroll
        for (int m = 0; m < 2; ++m)
            #pragma unroll
            for (int n = 0; n < 2; ++n) {
                int ch = w_h * 32 + 16 * n + l15;
                #pragma unroll
                for (int r = 0; r < 4; ++r) {
                    int e = w_e * 32 + 16 * m + 4 * lg + r;
                    red[widx(e, ch)] = __float_as_uint(acc2[m][n][r]);
                }
            }

        // ---- G: scratch visible ----
        asm volatile("s_waitcnt lgkmcnt(0)\n\ts_barrier" ::: "memory");

        // ---- H: segmented reduce (wave-uniform rows) + coalesced emit ----
        {
            int ch = tid & 63;
            int q  = tid >> 6;                 // wave id; edges 16q..16q+15
            int p0 = 16 * q;
            int currow = srow[ib][p0];
            float vmax = __uint_as_float(red[widx(p0, ch)]);
            #pragma unroll
            for (int j = 1; j < 16; ++j) {
                int row = srow[ib][p0 + j];
                float v = __uint_as_float(red[widx(p0 + j, ch)]);
                if (row != currow) {            // uniform across the wave
                    fmax_at(&acc[(size_t)currow * 128 + goff + ch], enc(vmax));
                    currow = row; vmax = v;
                } else {
                    vmax = fmaxf(vmax, v);
                }
            }
            fmax_at(&acc[(size_t)currow * 128 + goff + ch], enc(vmax));
        }
    }
}

extern "C" void kernel_launch(void* const* d_in, const int* in_sizes, int n_in,
                              void* d_out, int out_size, void* d_ws, size_t ws_size,
                              hipStream_t stream) {
    const float* x1 = (const float*)d_in[0];
    const float* x2 = (const float*)d_in[1];
    const int*   ei1 = (const int*)d_in[2];
    const int*   ei2 = (const int*)d_in[3];
    const float* W1 = (const float*)d_in[4];
    const float* b1 = (const float*)d_in[5];
    const float* W2 = (const float*)d_in[6];
    const float* b2 = (const float*)d_in[7];
    unsigned* acc = (unsigned*)d_out;

    // workspace layout (u32 units)
    unsigned* w = (unsigned*)d_ws;
    unsigned* cnt     = w;                    // 2*50000
    unsigned* partial = w + 100000;           // 2*98
    unsigned* boff    = w + 100200;           // 2*98
    unsigned* cur     = w + 100400;           // 2*50000
    uint2*    se      = (uint2*)(w + 200400); // 2*800000 uint2 (12.8 MB)

    hipMemsetAsync(cnt, 0, 2 * NN * sizeof(unsigned), stream);
    hipMemsetAsync(acc, 0, (size_t)NN * 128 * sizeof(unsigned), stream);

    hipLaunchKernelGGL(hist_k, dim3((2 * EE + 255) / 256), dim3(256), 0, stream,
                       ei1, ei2, cnt);
    hipLaunchKernelGGL(partial_k, dim3(2 * NB), dim3(512), 0, stream, cnt, partial);
    hipLaunchKernelGGL(boff_k, dim3(1), dim3(128), 0, stream, partial, boff);
    hipLaunchKernelGGL(cur_k, dim3(2 * NB), dim3(512), 0, stream, cnt, boff, cur);
    hipLaunchKernelGGL(scatter_k, dim3((2 * EE + 255) / 256), dim3(256), 0, stream,
                       ei1, ei2, cur, se);

    hipLaunchKernelGGL(edge_mlp, dim3(2 * BPG), dim3(256), 0, stream,
                       x1, x2, se, W1, b1, W2, b2, acc);
    hipLaunchKernelGGL(decode_acc, dim3((NN * 128 + 255) / 256), dim3(256), 0, stream,
                       acc, NN * 128);
}